// Round 1
// baseline (1015.436 us; speedup 1.0000x reference)
//
#include <hip/hip_runtime.h>

#define NN 100000
#define NE 3200000

// ---------------- init: deg=1 (self loop), cnt=0 ----------------
__global__ void k_init(float* __restrict__ deg, int* __restrict__ cnt, int n) {
    int i = blockIdx.x * 256 + threadIdx.x;
    if (i < n) { deg[i] = 1.0f; cnt[i] = 0; }
}

// ---------------- edge pass 1: weighted degree + per-dst edge count ----------------
__global__ void k_deg(const int* __restrict__ dst, const float* __restrict__ ew,
                      float* __restrict__ deg, int* __restrict__ cnt, int e) {
    int i = blockIdx.x * 256 + threadIdx.x;
    if (i < e) {
        int d = dst[i];
        atomicAdd(&deg[d], ew[i]);
        atomicAdd(&cnt[d], 1);
    }
}

// ---------------- scan stage 1: per-block exclusive scan (2048 elems/block) ----------------
#define SCAN_T 256
#define SCAN_E 8
__global__ void k_scan_blocks(const int* __restrict__ cnt, int* __restrict__ off,
                              int* __restrict__ bsum, int n) {
    __shared__ int sdata[SCAN_T];
    int base = blockIdx.x * (SCAN_T * SCAN_E);
    int t = threadIdx.x;
    int v[SCAN_E];
    int local = 0;
    int idx0 = base + t * SCAN_E;
#pragma unroll
    for (int i = 0; i < SCAN_E; i++) {
        int idx = idx0 + i;
        int c = (idx < n) ? cnt[idx] : 0;
        v[i] = local;
        local += c;
    }
    sdata[t] = local;
    __syncthreads();
    for (int o = 1; o < SCAN_T; o <<= 1) {
        int x = 0;
        if (t >= o) x = sdata[t - o];
        __syncthreads();
        sdata[t] += x;
        __syncthreads();
    }
    int excl = sdata[t] - local;
#pragma unroll
    for (int i = 0; i < SCAN_E; i++) {
        int idx = idx0 + i;
        if (idx < n) off[idx] = excl + v[i];
    }
    if (t == SCAN_T - 1) bsum[blockIdx.x] = sdata[t];
}

// ---------------- scan stage 2: exclusive scan of block sums (<=64) ----------------
__global__ void k_scan_bsums(int* __restrict__ bsum, int nb) {
    int t = threadIdx.x;  // 64 threads, 1 block
    int v = (t < nb) ? bsum[t] : 0;
    int orig = v;
#pragma unroll
    for (int o = 1; o < 64; o <<= 1) {
        int u = __shfl_up(v, o, 64);
        if (t >= o) v += u;
    }
    if (t < nb) bsum[t] = v - orig;
}

// ---------------- scan stage 3: add block offsets, copy cursor, deg->dinv ----------------
__global__ void k_finalize(int* __restrict__ off, const int* __restrict__ bsum,
                           int* __restrict__ cursor, float* __restrict__ deg,
                           int n, int total) {
    int i = blockIdx.x * 256 + threadIdx.x;
    if (i < n) {
        int o = off[i] + bsum[i >> 11];  // 2048 per scan block
        off[i] = o;
        cursor[i] = o;
        deg[i] = rsqrtf(deg[i]);  // deg >= 1 always (self loop), becomes dinv
    }
    if (i == 0) off[n] = total;
}

// ---------------- edge pass 2: bucket edges by dst (counting-sort scatter) ----------------
__global__ void k_scatter(const int* __restrict__ src, const int* __restrict__ dst,
                          const float* __restrict__ ew, const float* __restrict__ dinv,
                          int* __restrict__ cursor, int* __restrict__ ssrc,
                          float* __restrict__ snorm, int e) {
    int i = blockIdx.x * 256 + threadIdx.x;
    if (i < e) {
        int s = src[i], d = dst[i];
        float nm = dinv[s] * ew[i] * dinv[d];
        int pos = atomicAdd(&cursor[d], 1);
        ssrc[pos] = s;
        snorm[pos] = nm;
    }
}

// ---------------- GEMM: h[N,64] = x[N,256] @ W[256,64] ----------------
#define GR 128      // rows per block
#define GKC 64      // k-chunk
#define XS_STRIDE 68
__global__ __launch_bounds__(256) void k_gemm(const float* __restrict__ x,
                                              const float* __restrict__ W,
                                              float* __restrict__ h, int n) {
    __shared__ float xs[GR][XS_STRIDE];  // [row][k-within-chunk], padded
    __shared__ float wsh[GKC][64];       // [k-within-chunk][col]
    int t = threadIdx.x;
    int tx = t & 15;        // col group: cols tx*4 .. tx*4+3
    int ty = t >> 4;        // row group: rows ty*8 .. ty*8+7
    int rbase = blockIdx.x * GR;
    float acc[8][4];
#pragma unroll
    for (int i = 0; i < 8; i++)
#pragma unroll
        for (int j = 0; j < 4; j++) acc[i][j] = 0.0f;

    for (int k0 = 0; k0 < 256; k0 += GKC) {
        // stage W chunk: rows k0..k0+63 of W are 4096 contiguous floats
        const float4* wsrc = (const float4*)(W + k0 * 64);
        float4* wdst = (float4*)(&wsh[0][0]);
#pragma unroll
        for (int p = 0; p < 4; p++) wdst[p * 256 + t] = wsrc[p * 256 + t];
        // stage x chunk: 128 rows x 64 k
#pragma unroll
        for (int p = 0; p < 8; p++) {
            int f4 = p * 256 + t;        // 0..2047
            int r = f4 >> 4;             // row within tile
            int kq = (f4 & 15) << 2;     // k within chunk (float4 granularity)
            int row = rbase + r;
            float4 val = make_float4(0.f, 0.f, 0.f, 0.f);
            if (row < n) val = *(const float4*)(x + row * 256 + k0 + kq);
            *(float4*)(&xs[r][kq]) = val;
        }
        __syncthreads();
        int r0 = ty * 8, c0 = tx * 4;
#pragma unroll
        for (int kk = 0; kk < GKC; kk += 4) {
            float4 wv[4];
#pragma unroll
            for (int m = 0; m < 4; m++) wv[m] = *(const float4*)(&wsh[kk + m][c0]);
#pragma unroll
            for (int i = 0; i < 8; i++) {
                float4 xv = *(const float4*)(&xs[r0 + i][kk]);
                acc[i][0] += xv.x * wv[0].x + xv.y * wv[1].x + xv.z * wv[2].x + xv.w * wv[3].x;
                acc[i][1] += xv.x * wv[0].y + xv.y * wv[1].y + xv.z * wv[2].y + xv.w * wv[3].y;
                acc[i][2] += xv.x * wv[0].z + xv.y * wv[1].z + xv.z * wv[2].z + xv.w * wv[3].z;
                acc[i][3] += xv.x * wv[0].w + xv.y * wv[1].w + xv.z * wv[2].w + xv.w * wv[3].w;
            }
        }
        __syncthreads();
    }
    int r0 = ty * 8, c0 = tx * 4;
#pragma unroll
    for (int i = 0; i < 8; i++) {
        int row = rbase + r0 + i;
        if (row < n) {
            float4 v = make_float4(acc[i][0], acc[i][1], acc[i][2], acc[i][3]);
            *(float4*)(h + row * 64 + c0) = v;
        }
    }
}

// ---------------- gather + bias + leaky-relu + layernorm ----------------
__global__ __launch_bounds__(256) void k_gather(
    const float* __restrict__ h, const float* __restrict__ dinv,
    const int* __restrict__ off, const int* __restrict__ ssrc,
    const float* __restrict__ snorm, const float* __restrict__ bias,
    const float* __restrict__ gamma, const float* __restrict__ beta,
    float* __restrict__ out, int n) {
    int lane = threadIdx.x & 63;
    int wid = threadIdx.x >> 6;
    int node = blockIdx.x * 4 + wid;
    if (node >= n) return;
    float di = dinv[node];
    float acc = h[node * 64 + lane] * di * di;  // self-loop (weight 1)
    int beg = off[node], end = off[node + 1];
    for (int j = beg; j < end; j += 64) {
        int cnt = end - j;
        if (cnt > 64) cnt = 64;
        int s = 0;
        float w = 0.f;
        if (lane < cnt) { s = ssrc[j + lane]; w = snorm[j + lane]; }
        for (int i2 = 0; i2 < cnt; i2++) {
            int si = __shfl(s, i2, 64);
            float wi = __shfl(w, i2, 64);
            acc += h[si * 64 + lane] * wi;
        }
    }
    float y = acc + bias[lane];
    y = (y >= 0.f) ? y : 0.01f * y;  // leaky relu
    float sum = y;
#pragma unroll
    for (int o = 32; o > 0; o >>= 1) sum += __shfl_xor(sum, o, 64);
    float mu = sum * (1.0f / 64.0f);
    float d = y - mu;
    float v = d * d;
#pragma unroll
    for (int o = 32; o > 0; o >>= 1) v += __shfl_xor(v, o, 64);
    v *= (1.0f / 64.0f);
    out[node * 64 + lane] = d * rsqrtf(v + 1e-5f) * gamma[lane] + beta[lane];
}

extern "C" void kernel_launch(void* const* d_in, const int* in_sizes, int n_in,
                              void* d_out, int out_size, void* d_ws, size_t ws_size,
                              hipStream_t stream) {
    const float* x = (const float*)d_in[0];
    const int* ei = (const int*)d_in[1];
    const float* ew = (const float*)d_in[2];
    const float* W = (const float*)d_in[3];
    const float* b = (const float*)d_in[4];
    const float* gamma = (const float*)d_in[5];
    const float* beta = (const float*)d_in[6];
    float* out = (float*)d_out;

    const int n = NN, e = NE;
    const int* src = ei;
    const int* dst = ei + e;

    char* ws = (char*)d_ws;
    size_t o = 0;
    auto alloc = [&](size_t bytes) -> char* {
        char* r = ws + o;
        o = (o + bytes + 255) & ~(size_t)255;
        return r;
    };
    float* deg = (float*)alloc((size_t)n * 4);        // becomes dinv in k_finalize
    int* cnt = (int*)alloc((size_t)n * 4);
    int* off = (int*)alloc((size_t)(n + 1) * 4);
    int* cursor = (int*)alloc((size_t)n * 4);
    int* bsum = (int*)alloc(64 * 4);
    float* h = (float*)alloc((size_t)n * 64 * 4);
    int* ssrc = (int*)alloc((size_t)e * 4);
    float* snorm = (float*)alloc((size_t)e * 4);
    (void)ws_size;

    int nb_n = (n + 255) / 256;
    int nb_e = (e + 255) / 256;
    int nb_scan = (n + SCAN_T * SCAN_E - 1) / (SCAN_T * SCAN_E);  // 49
    int nb_gemm = (n + GR - 1) / GR;
    int nb_gather = (n + 3) / 4;

    k_init<<<nb_n, 256, 0, stream>>>(deg, cnt, n);
    k_deg<<<nb_e, 256, 0, stream>>>(dst, ew, deg, cnt, e);
    k_scan_blocks<<<nb_scan, SCAN_T, 0, stream>>>(cnt, off, bsum, n);
    k_scan_bsums<<<1, 64, 0, stream>>>(bsum, nb_scan);
    k_finalize<<<nb_n, 256, 0, stream>>>(off, bsum, cursor, deg, n, e);
    k_scatter<<<nb_e, 256, 0, stream>>>(src, dst, ew, deg, cursor, ssrc, snorm, e);
    k_gemm<<<nb_gemm, 256, 0, stream>>>(x, W, h, n);
    k_gather<<<nb_gather, 256, 0, stream>>>(h, deg, off, ssrc, snorm, b, gamma, beta, out, n);
}

// Round 2
// 743.890 us; speedup vs baseline: 1.3650x; 1.3650x over previous
//
#include <hip/hip_runtime.h>

#define NN 100000
#define NE 3200000
#define OVCAP 65536

struct OvEnt { int dst; int src; float ew; int pad; };

// ================= bucket pipeline =================

__global__ void k_zero(int* __restrict__ cursor, int* __restrict__ ovcnt, int n) {
    int i = blockIdx.x * 256 + threadIdx.x;
    if (i < n) cursor[i] = 0;
    if (i == 0) *ovcnt = 0;
}

__global__ void k_scatter_b(const int* __restrict__ src, const int* __restrict__ dst,
                            const float* __restrict__ ew, int* __restrict__ cursor,
                            uint2* __restrict__ bucket, int cap,
                            OvEnt* __restrict__ ov, int* __restrict__ ovcnt, int e) {
    int i = blockIdx.x * 256 + threadIdx.x;
    if (i < e) {
        int s = src[i], d = dst[i];
        float w = ew[i];
        int pos = atomicAdd(&cursor[d], 1);
        if (pos < cap) {
            bucket[(size_t)d * cap + pos] = make_uint2((unsigned)s, __float_as_uint(w));
        } else {
            int op = atomicAdd(ovcnt, 1);
            if (op < OVCAP) { OvEnt t; t.dst = d; t.src = s; t.ew = w; t.pad = 0; ov[op] = t; }
        }
    }
}

__global__ __launch_bounds__(256) void k_dinv(const int* __restrict__ cursor,
                                              const uint2* __restrict__ bucket, int cap,
                                              const OvEnt* __restrict__ ov,
                                              const int* __restrict__ ovcnt,
                                              float* __restrict__ dinv, int n) {
    int lane = threadIdx.x & 63, wid = threadIdx.x >> 6;
    int node = blockIdx.x * 4 + wid;
    if (node >= n) return;
    int cnt = cursor[node];
    int bc = cnt < cap ? cnt : cap;
    const uint2* bk = bucket + (size_t)node * cap;
    float s = 0.f;
    for (int j = lane; j < bc; j += 64) s += __uint_as_float(bk[j].y);
    if (cnt > cap) {
        int on = *ovcnt; if (on > OVCAP) on = OVCAP;
        for (int j = lane; j < on; j += 64)
            if (ov[j].dst == node) s += ov[j].ew;
    }
#pragma unroll
    for (int o = 32; o > 0; o >>= 1) s += __shfl_xor(s, o, 64);
    if (lane == 0) dinv[node] = rsqrtf(1.0f + s);
}

__global__ __launch_bounds__(256) void k_gather_b(
    const float* __restrict__ h, const float* __restrict__ dinv,
    const int* __restrict__ cursor, const uint2* __restrict__ bucket, int cap,
    const OvEnt* __restrict__ ov, const int* __restrict__ ovcnt,
    const float* __restrict__ bias, const float* __restrict__ gamma,
    const float* __restrict__ beta, float* __restrict__ out, int n) {
    int lane = threadIdx.x & 63, wid = threadIdx.x >> 6;
    int node = blockIdx.x * 4 + wid;
    if (node >= n) return;
    float di = dinv[node];
    float acc = h[(size_t)node * 64 + lane] * di * di;  // self loop, weight 1
    int cnt = cursor[node];
    int bc = cnt < cap ? cnt : cap;
    const uint2* bk = bucket + (size_t)node * cap;
    for (int j = 0; j < bc; j += 64) {
        int c = bc - j; if (c > 64) c = 64;
        int s = 0; float w = 0.f;
        if (lane < c) {
            uint2 v = bk[j + lane];
            s = (int)v.x;
            w = __uint_as_float(v.y) * dinv[s] * di;
        }
        for (int i2 = 0; i2 < c; i2++) {
            int si = __shfl(s, i2, 64);
            float wi = __shfl(w, i2, 64);
            acc += h[(size_t)si * 64 + lane] * wi;
        }
    }
    if (cnt > cap) {
        int on = *ovcnt; if (on > OVCAP) on = OVCAP;
        for (int j = 0; j < on; j++) {
            OvEnt ent = ov[j];
            if (ent.dst == node)
                acc += h[(size_t)ent.src * 64 + lane] * dinv[ent.src] * ent.ew * di;
        }
    }
    float y = acc + bias[lane];
    y = (y >= 0.f) ? y : 0.01f * y;
    float sum = y;
#pragma unroll
    for (int o = 32; o > 0; o >>= 1) sum += __shfl_xor(sum, o, 64);
    float mu = sum * (1.0f / 64.0f);
    float d = y - mu;
    float v = d * d;
#pragma unroll
    for (int o = 32; o > 0; o >>= 1) v += __shfl_xor(v, o, 64);
    v *= (1.0f / 64.0f);
    out[(size_t)node * 64 + lane] = d * rsqrtf(v + 1e-5f) * gamma[lane] + beta[lane];
}

// ================= GEMM: h[N,64] = x[N,256] @ W[256,64] =================
#define GR 128
#define GKC 64
#define XS_STRIDE 68
__global__ __launch_bounds__(256) void k_gemm(const float* __restrict__ x,
                                              const float* __restrict__ W,
                                              float* __restrict__ h, int n) {
    __shared__ float xs[GR][XS_STRIDE];
    __shared__ float wsh[GKC][64];
    int t = threadIdx.x;
    int tx = t & 15;
    int ty = t >> 4;
    int rbase = blockIdx.x * GR;
    float acc[8][4];
#pragma unroll
    for (int i = 0; i < 8; i++)
#pragma unroll
        for (int j = 0; j < 4; j++) acc[i][j] = 0.0f;

    for (int k0 = 0; k0 < 256; k0 += GKC) {
        const float4* wsrc = (const float4*)(W + k0 * 64);
        float4* wdst = (float4*)(&wsh[0][0]);
#pragma unroll
        for (int p = 0; p < 4; p++) wdst[p * 256 + t] = wsrc[p * 256 + t];
#pragma unroll
        for (int p = 0; p < 8; p++) {
            int f4 = p * 256 + t;
            int r = f4 >> 4;
            int kq = (f4 & 15) << 2;
            int row = rbase + r;
            float4 val = make_float4(0.f, 0.f, 0.f, 0.f);
            if (row < n) val = *(const float4*)(x + (size_t)row * 256 + k0 + kq);
            *(float4*)(&xs[r][kq]) = val;
        }
        __syncthreads();
        int r0 = ty * 8, c0 = tx * 4;
#pragma unroll
        for (int kk = 0; kk < GKC; kk += 4) {
            float4 wv[4];
#pragma unroll
            for (int m = 0; m < 4; m++) wv[m] = *(const float4*)(&wsh[kk + m][c0]);
#pragma unroll
            for (int i = 0; i < 8; i++) {
                float4 xv = *(const float4*)(&xs[r0 + i][kk]);
                acc[i][0] += xv.x * wv[0].x + xv.y * wv[1].x + xv.z * wv[2].x + xv.w * wv[3].x;
                acc[i][1] += xv.x * wv[0].y + xv.y * wv[1].y + xv.z * wv[2].y + xv.w * wv[3].y;
                acc[i][2] += xv.x * wv[0].z + xv.y * wv[1].z + xv.z * wv[2].z + xv.w * wv[3].z;
                acc[i][3] += xv.x * wv[0].w + xv.y * wv[1].w + xv.z * wv[2].w + xv.w * wv[3].w;
            }
        }
        __syncthreads();
    }
    int r0 = ty * 8, c0 = tx * 4;
#pragma unroll
    for (int i = 0; i < 8; i++) {
        int row = rbase + r0 + i;
        if (row < n) {
            float4 v = make_float4(acc[i][0], acc[i][1], acc[i][2], acc[i][3]);
            *(float4*)(h + (size_t)row * 64 + c0) = v;
        }
    }
}

// ================= fallback pipeline (round-1, proven) =================

__global__ void k_init(float* __restrict__ deg, int* __restrict__ cnt, int n) {
    int i = blockIdx.x * 256 + threadIdx.x;
    if (i < n) { deg[i] = 1.0f; cnt[i] = 0; }
}

__global__ void k_deg(const int* __restrict__ dst, const float* __restrict__ ew,
                      float* __restrict__ deg, int* __restrict__ cnt, int e) {
    int i = blockIdx.x * 256 + threadIdx.x;
    if (i < e) {
        int d = dst[i];
        atomicAdd(&deg[d], ew[i]);
        atomicAdd(&cnt[d], 1);
    }
}

#define SCAN_T 256
#define SCAN_E 8
__global__ void k_scan_blocks(const int* __restrict__ cnt, int* __restrict__ off,
                              int* __restrict__ bsum, int n) {
    __shared__ int sdata[SCAN_T];
    int base = blockIdx.x * (SCAN_T * SCAN_E);
    int t = threadIdx.x;
    int v[SCAN_E];
    int local = 0;
    int idx0 = base + t * SCAN_E;
#pragma unroll
    for (int i = 0; i < SCAN_E; i++) {
        int idx = idx0 + i;
        int c = (idx < n) ? cnt[idx] : 0;
        v[i] = local;
        local += c;
    }
    sdata[t] = local;
    __syncthreads();
    for (int o = 1; o < SCAN_T; o <<= 1) {
        int x = 0;
        if (t >= o) x = sdata[t - o];
        __syncthreads();
        sdata[t] += x;
        __syncthreads();
    }
    int excl = sdata[t] - local;
#pragma unroll
    for (int i = 0; i < SCAN_E; i++) {
        int idx = idx0 + i;
        if (idx < n) off[idx] = excl + v[i];
    }
    if (t == SCAN_T - 1) bsum[blockIdx.x] = sdata[t];
}

__global__ void k_scan_bsums(int* __restrict__ bsum, int nb) {
    int t = threadIdx.x;
    int v = (t < nb) ? bsum[t] : 0;
    int orig = v;
#pragma unroll
    for (int o = 1; o < 64; o <<= 1) {
        int u = __shfl_up(v, o, 64);
        if (t >= o) v += u;
    }
    if (t < nb) bsum[t] = v - orig;
}

__global__ void k_finalize(int* __restrict__ off, const int* __restrict__ bsum,
                           int* __restrict__ cursor, float* __restrict__ deg,
                           int n, int total) {
    int i = blockIdx.x * 256 + threadIdx.x;
    if (i < n) {
        int o = off[i] + bsum[i >> 11];
        off[i] = o;
        cursor[i] = o;
        deg[i] = rsqrtf(deg[i]);
    }
    if (i == 0) off[n] = total;
}

__global__ void k_scatter(const int* __restrict__ src, const int* __restrict__ dst,
                          const float* __restrict__ ew, const float* __restrict__ dinv,
                          int* __restrict__ cursor, int* __restrict__ ssrc,
                          float* __restrict__ snorm, int e) {
    int i = blockIdx.x * 256 + threadIdx.x;
    if (i < e) {
        int s = src[i], d = dst[i];
        float nm = dinv[s] * ew[i] * dinv[d];
        int pos = atomicAdd(&cursor[d], 1);
        ssrc[pos] = s;
        snorm[pos] = nm;
    }
}

__global__ __launch_bounds__(256) void k_gather(
    const float* __restrict__ h, const float* __restrict__ dinv,
    const int* __restrict__ off, const int* __restrict__ ssrc,
    const float* __restrict__ snorm, const float* __restrict__ bias,
    const float* __restrict__ gamma, const float* __restrict__ beta,
    float* __restrict__ out, int n) {
    int lane = threadIdx.x & 63;
    int wid = threadIdx.x >> 6;
    int node = blockIdx.x * 4 + wid;
    if (node >= n) return;
    float di = dinv[node];
    float acc = h[(size_t)node * 64 + lane] * di * di;
    int beg = off[node], end = off[node + 1];
    for (int j = beg; j < end; j += 64) {
        int cnt = end - j;
        if (cnt > 64) cnt = 64;
        int s = 0;
        float w = 0.f;
        if (lane < cnt) { s = ssrc[j + lane]; w = snorm[j + lane]; }
        for (int i2 = 0; i2 < cnt; i2++) {
            int si = __shfl(s, i2, 64);
            float wi = __shfl(w, i2, 64);
            acc += h[(size_t)si * 64 + lane] * wi;
        }
    }
    float y = acc + bias[lane];
    y = (y >= 0.f) ? y : 0.01f * y;
    float sum = y;
#pragma unroll
    for (int o = 32; o > 0; o >>= 1) sum += __shfl_xor(sum, o, 64);
    float mu = sum * (1.0f / 64.0f);
    float d = y - mu;
    float v = d * d;
#pragma unroll
    for (int o = 32; o > 0; o >>= 1) v += __shfl_xor(v, o, 64);
    v *= (1.0f / 64.0f);
    out[(size_t)node * 64 + lane] = d * rsqrtf(v + 1e-5f) * gamma[lane] + beta[lane];
}

// ================= launch =================

extern "C" void kernel_launch(void* const* d_in, const int* in_sizes, int n_in,
                              void* d_out, int out_size, void* d_ws, size_t ws_size,
                              hipStream_t stream) {
    const float* x = (const float*)d_in[0];
    const int* ei = (const int*)d_in[1];
    const float* ew = (const float*)d_in[2];
    const float* W = (const float*)d_in[3];
    const float* b = (const float*)d_in[4];
    const float* gamma = (const float*)d_in[5];
    const float* beta = (const float*)d_in[6];
    float* out = (float*)d_out;

    const int n = NN, e = NE;
    const int* src = ei;
    const int* dst = ei + e;

    char* ws = (char*)d_ws;
    size_t o = 0;
    auto alloc = [&](size_t bytes) -> char* {
        char* r = ws + o;
        o = (o + bytes + 255) & ~(size_t)255;
        return r;
    };

    int nb_n = (n + 255) / 256;
    int nb_e = (e + 255) / 256;
    int nb_gemm = (n + GR - 1) / GR;
    int nb_w = (n + 3) / 4;

    // fixed allocations for the bucket pipeline
    size_t fixed = 0;
    fixed += ((size_t)n * 4 + 255) & ~(size_t)255;        // cursor
    fixed += 256;                                          // ovcnt
    fixed += ((size_t)OVCAP * 16 + 255) & ~(size_t)255;    // ov
    fixed += ((size_t)n * 4 + 255) & ~(size_t)255;         // dinv
    fixed += ((size_t)n * 64 * 4 + 255) & ~(size_t)255;    // h

    int cap = 0;
    if (ws_size >= fixed + (size_t)n * 96 * 8 + 1024) cap = 96;
    else if (ws_size >= fixed + (size_t)n * 64 * 8 + 1024) cap = 64;
    else if (ws_size >= fixed + (size_t)n * 56 * 8 + 1024) cap = 56;

    if (cap > 0) {
        int* cursor = (int*)alloc((size_t)n * 4);
        int* ovcnt = (int*)alloc(4);
        OvEnt* ov = (OvEnt*)alloc((size_t)OVCAP * 16);
        float* dinv = (float*)alloc((size_t)n * 4);
        float* h = (float*)alloc((size_t)n * 64 * 4);
        uint2* bucket = (uint2*)alloc((size_t)n * cap * 8);

        k_zero<<<nb_n, 256, 0, stream>>>(cursor, ovcnt, n);
        k_scatter_b<<<nb_e, 256, 0, stream>>>(src, dst, ew, cursor, bucket, cap, ov, ovcnt, e);
        k_dinv<<<nb_w, 256, 0, stream>>>(cursor, bucket, cap, ov, ovcnt, dinv, n);
        k_gemm<<<nb_gemm, 256, 0, stream>>>(x, W, h, n);
        k_gather_b<<<nb_w, 256, 0, stream>>>(h, dinv, cursor, bucket, cap, ov, ovcnt,
                                             b, gamma, beta, out, n);
    } else {
        // fallback: round-1 pipeline
        float* deg = (float*)alloc((size_t)n * 4);
        int* cnt = (int*)alloc((size_t)n * 4);
        int* off = (int*)alloc((size_t)(n + 1) * 4);
        int* cursor = (int*)alloc((size_t)n * 4);
        int* bsum = (int*)alloc(64 * 4);
        float* h = (float*)alloc((size_t)n * 64 * 4);
        int* ssrc = (int*)alloc((size_t)e * 4);
        float* snorm = (float*)alloc((size_t)e * 4);
        int nb_scan = (n + SCAN_T * SCAN_E - 1) / (SCAN_T * SCAN_E);

        k_init<<<nb_n, 256, 0, stream>>>(deg, cnt, n);
        k_deg<<<nb_e, 256, 0, stream>>>(dst, ew, deg, cnt, e);
        k_scan_blocks<<<nb_scan, SCAN_T, 0, stream>>>(cnt, off, bsum, n);
        k_scan_bsums<<<1, 64, 0, stream>>>(bsum, nb_scan);
        k_finalize<<<nb_n, 256, 0, stream>>>(off, bsum, cursor, deg, n, e);
        k_scatter<<<nb_e, 256, 0, stream>>>(src, dst, ew, deg, cursor, ssrc, snorm, e);
        k_gemm<<<nb_gemm, 256, 0, stream>>>(x, W, h, n);
        k_gather<<<nb_w, 256, 0, stream>>>(h, deg, off, ssrc, snorm, b, gamma, beta, out, n);
    }
}